// Round 1
// baseline (156.152 us; speedup 1.0000x reference)
//
#include <hip/hip_runtime.h>

#define V_SZ 45
#define H_SZ 2048
#define W_SZ 128
#define D_SZ 200
#define X_SZ (H_SZ + W_SZ)               // 2176
#define STACK_BLKS ((D_SZ * W_SZ) / 256)  // 100

// ws layout (floats)
#define WS_CTRL 0     // 3 ctrl logits
#define WS_SIN  16    // 128 stack_input (tanh'd), float4-aligned
#define WS_HNEW 160   // 2048 h_new (f32)

typedef float f4 __attribute__((ext_vector_type(4)));

__device__ __forceinline__ float dot4(f4 a, f4 b) {
  return a.x * b.x + a.y * b.y + a.z * b.z + a.w * b.w;
}

// non-temporal load: keep single-use weight streams out of L2 so the
// hidden/emb broadcast rows stay resident for all 2048 blocks.
__device__ __forceinline__ f4 ldnt(const f4* p) {
  return __builtin_nontemporal_load(p);
}

__device__ __forceinline__ float wave_reduce(float v) {
#pragma unroll
  for (int o = 32; o > 0; o >>= 1) v += __shfl_down(v, o, 64);
  return v;
}

// softmax over the 3 ctrl logits stored in ws
__device__ __forceinline__ void ctrl_softmax(const float* __restrict__ ws,
                                             float& c0, float& c1, float& c2) {
  const float l0 = ws[WS_CTRL + 0], l1 = ws[WS_CTRL + 1], l2 = ws[WS_CTRL + 2];
  const float m = fmaxf(l0, fmaxf(l1, l2));
  const float e0 = __expf(l0 - m), e1 = __expf(l1 - m), e2 = __expf(l2 - m);
  const float inv = 1.f / (e0 + e1 + e2);
  c0 = e0 * inv; c1 = e1 * inv; c2 = e2 * inv;
}

// ---------------------------------------------------------------------------
// K1: ctrl logits (3 rows) + stack_input = tanh(h @ sin_W.T + sin_b) (128 rows)
// one block per output row; 2048-long dot, 256 threads x 8 floats (2x float4)
// ---------------------------------------------------------------------------
__global__ __launch_bounds__(256) void k1_small_gemv(
    const float* __restrict__ hidden,
    const float* __restrict__ ctrl_W,
    const float* __restrict__ ctrl_b,
    const float* __restrict__ sin_W,
    const float* __restrict__ sin_b,
    float* __restrict__ ws) {
  const int b = blockIdx.x;   // 0..130
  const int tid = threadIdx.x;
  const float* row = (b < 3) ? (ctrl_W + (size_t)b * H_SZ)
                             : (sin_W + (size_t)(b - 3) * H_SZ);
  const f4* rw4 = (const f4*)row;
  const f4* rh4 = (const f4*)hidden;
  float acc = dot4(rw4[tid], rh4[tid]) + dot4(rw4[tid + 256], rh4[tid + 256]);

  acc = wave_reduce(acc);
  __shared__ float red[4];
  const int wv_id = tid >> 6;
  if ((tid & 63) == 0) red[wv_id] = acc;
  __syncthreads();
  if (tid == 0) {
    float total = red[0] + red[1] + red[2] + red[3];
    if (b < 3) {
      ws[WS_CTRL + b] = total + ctrl_b[b];
    } else {
      ws[WS_SIN + (b - 3)] = tanhf(total + sin_b[b - 3]);
    }
  }
}

// ---------------------------------------------------------------------------
// K3: blocks 0..99            -> new_stack elements (depend only on K1's ws)
//     blocks 100..100+2047    -> fused GRU GEMV: block j computes 6 dots
//     (w_ih rows j, j+H, j+2H over x; w_hh rows j, j+H, j+2H over h),
//     gates, h_new[j].
// x is never materialized: emb part read straight from emb (L2-broadcast),
// stack_top chunks computed inline from ws logits/sin + stack rows 0,1.
// Weight rows use non-temporal loads (single-use stream; protect L2).
// ---------------------------------------------------------------------------
__global__ __launch_bounds__(256) void k3_gru_stack(
    const int* __restrict__ inp,
    const float* __restrict__ hidden,
    const float* __restrict__ emb,
    const float* __restrict__ stack,
    const float* __restrict__ w_ih,
    const float* __restrict__ w_hh,
    const float* __restrict__ b_ih,
    const float* __restrict__ b_hh,
    float* __restrict__ ws,
    float* __restrict__ out) {
  const int tid = threadIdx.x;

  if (blockIdx.x < STACK_BLKS) {
    // new_stack: 25600 elements across 100 blocks, overlapped with the GEMV
    const int i = blockIdx.x * 256 + tid;   // 0 .. 25599
    float c0, c1, c2;
    ctrl_softmax(ws, c0, c1, c2);
    const int d = i >> 7;          // / W_SZ
    const int w = i & (W_SZ - 1);  // % W_SZ
    const float s = stack[i];
    const float up = (d == 0) ? ws[WS_SIN + w] : stack[i - W_SZ];
    const float dn = (d == D_SZ - 1) ? 0.f : stack[i + W_SZ];
    out[V_SZ + H_SZ + i] = c2 * s + c0 * up + c1 * dn;
    return;
  }

  const int j = blockIdx.x - STACK_BLKS;

  // prefetch tail-combine scalars early so their latency hides under the
  // main streaming loop (they are only consumed by tid 0 at the very end)
  float bi0 = 0.f, bi1 = 0.f, bi2 = 0.f;
  float bh0 = 0.f, bh1 = 0.f, bh2 = 0.f, hj = 0.f;
  if (tid == 0) {
    bi0 = b_ih[j]; bi1 = b_ih[j + H_SZ]; bi2 = b_ih[j + 2 * H_SZ];
    bh0 = b_hh[j]; bh1 = b_hh[j + H_SZ]; bh2 = b_hh[j + 2 * H_SZ];
    hj  = hidden[j];
  }

  float a0 = 0.f, a1 = 0.f, a2 = 0.f, a3 = 0.f, a4 = 0.f, a5 = 0.f;

  const f4* wi0 = (const f4*)(w_ih + (size_t)j * X_SZ);
  const f4* wi1 = (const f4*)(w_ih + (size_t)(j + H_SZ) * X_SZ);
  const f4* wi2 = (const f4*)(w_ih + (size_t)(j + 2 * H_SZ) * X_SZ);
  const f4* emb4 = (const f4*)(emb + (size_t)inp[0] * H_SZ);

  // chunks 0..511: x = emb row (L2-cached broadcast)
#pragma unroll
  for (int q = 0; q < 2; ++q) {
    const int c = tid + q * 256;
    const f4 xv = emb4[c];
    a0 += dot4(ldnt(wi0 + c), xv);
    a1 += dot4(ldnt(wi1 + c), xv);
    a2 += dot4(ldnt(wi2 + c), xv);
  }
  // chunks 512..543: x = stack_top, computed inline (32 threads)
  if (tid < (X_SZ - H_SZ) / 4) {
    const int c = 512 + tid;
    const int w = 4 * tid;
    float c0, c1, c2;
    ctrl_softmax(ws, c0, c1, c2);
    const f4 s0 = *(const f4*)(stack + w);          // stack row 0
    const f4 s1 = *(const f4*)(stack + W_SZ + w);   // stack row 1
    const f4 sv = *(const f4*)(ws + WS_SIN + w);    // tanh(sin)
    f4 xv;
    xv.x = c2 * s0.x + c0 * sv.x + c1 * s1.x;
    xv.y = c2 * s0.y + c0 * sv.y + c1 * s1.y;
    xv.z = c2 * s0.z + c0 * sv.z + c1 * s1.z;
    xv.w = c2 * s0.w + c0 * sv.w + c1 * s1.w;
    a0 += dot4(ldnt(wi0 + c), xv);
    a1 += dot4(ldnt(wi1 + c), xv);
    a2 += dot4(ldnt(wi2 + c), xv);
  }

  const f4* wh0 = (const f4*)(w_hh + (size_t)j * H_SZ);
  const f4* wh1 = (const f4*)(w_hh + (size_t)(j + H_SZ) * H_SZ);
  const f4* wh2 = (const f4*)(w_hh + (size_t)(j + 2 * H_SZ) * H_SZ);
  const f4* h4 = (const f4*)hidden;
#pragma unroll
  for (int q = 0; q < 2; ++q) {
    const int c = tid + q * 256;
    const f4 hv = h4[c];
    a3 += dot4(ldnt(wh0 + c), hv);
    a4 += dot4(ldnt(wh1 + c), hv);
    a5 += dot4(ldnt(wh2 + c), hv);
  }

  a0 = wave_reduce(a0); a1 = wave_reduce(a1); a2 = wave_reduce(a2);
  a3 = wave_reduce(a3); a4 = wave_reduce(a4); a5 = wave_reduce(a5);
  __shared__ float red[4][6];
  const int wv_id = tid >> 6;
  if ((tid & 63) == 0) {
    red[wv_id][0] = a0; red[wv_id][1] = a1; red[wv_id][2] = a2;
    red[wv_id][3] = a3; red[wv_id][4] = a4; red[wv_id][5] = a5;
  }
  __syncthreads();
  if (tid == 0) {
    float t[6];
#pragma unroll
    for (int q = 0; q < 6; ++q)
      t[q] = red[0][q] + red[1][q] + red[2][q] + red[3][q];
    const float gi_r = t[0] + bi0;
    const float gi_z = t[1] + bi1;
    const float gi_n = t[2] + bi2;
    const float gh_r = t[3] + bh0;
    const float gh_z = t[4] + bh1;
    const float gh_n = t[5] + bh2;
    const float r = 1.f / (1.f + __expf(-(gi_r + gh_r)));
    const float z = 1.f / (1.f + __expf(-(gi_z + gh_z)));
    const float n = tanhf(gi_n + r * gh_n);
    const float hn = (1.f - z) * n + z * hj;
    ws[WS_HNEW + j] = hn;
    out[V_SZ + j] = hn;
  }
}

// ---------------------------------------------------------------------------
// K4: 45 blocks -> output logits = h_new @ dec_W.T + dec_b
// ---------------------------------------------------------------------------
__global__ __launch_bounds__(256) void k4_dec(
    const float* __restrict__ dec_W,
    const float* __restrict__ dec_b,
    const float* __restrict__ ws,
    float* __restrict__ out) {
  const int v = blockIdx.x;
  const int tid = threadIdx.x;
  float db = 0.f;
  if (tid == 0) db = dec_b[v];   // prefetch early
  const f4* row = (const f4*)(dec_W + (size_t)v * H_SZ);
  const f4* h4 = (const f4*)(ws + WS_HNEW);
  float acc = dot4(row[tid], h4[tid]) + dot4(row[tid + 256], h4[tid + 256]);
  acc = wave_reduce(acc);
  __shared__ float red[4];
  const int wv_id = tid >> 6;
  if ((tid & 63) == 0) red[wv_id] = acc;
  __syncthreads();
  if (tid == 0) out[v] = red[0] + red[1] + red[2] + red[3] + db;
}

extern "C" void kernel_launch(void* const* d_in, const int* in_sizes, int n_in,
                              void* d_out, int out_size, void* d_ws, size_t ws_size,
                              hipStream_t stream) {
  const int*   inp    = (const int*)d_in[0];
  const float* hidden = (const float*)d_in[1];
  const float* stack  = (const float*)d_in[2];
  const float* emb    = (const float*)d_in[3];
  const float* ctrl_W = (const float*)d_in[4];
  const float* ctrl_b = (const float*)d_in[5];
  const float* sin_W  = (const float*)d_in[6];
  const float* sin_b  = (const float*)d_in[7];
  const float* w_ih   = (const float*)d_in[8];
  const float* w_hh   = (const float*)d_in[9];
  const float* b_ih   = (const float*)d_in[10];
  const float* b_hh   = (const float*)d_in[11];
  const float* dec_W  = (const float*)d_in[12];
  const float* dec_b  = (const float*)d_in[13];
  float* out = (float*)d_out;
  float* ws = (float*)d_ws;

  k1_small_gemv<<<3 + W_SZ, 256, 0, stream>>>(hidden, ctrl_W, ctrl_b, sin_W, sin_b, ws);
  k3_gru_stack<<<STACK_BLKS + H_SZ, 256, 0, stream>>>(inp, hidden, emb, stack,
                                                      w_ih, w_hh, b_ih, b_hh, ws, out);
  k4_dec<<<V_SZ, 256, 0, stream>>>(dec_W, dec_b, ws, out);
}

// Round 2
// 154.054 us; speedup vs baseline: 1.0136x; 1.0136x over previous
//
#include <hip/hip_runtime.h>

#define V_SZ 45
#define H_SZ 2048
#define W_SZ 128
#define D_SZ 200
#define X_SZ (H_SZ + W_SZ)                // 2176
#define STACK_BLKS ((D_SZ * W_SZ) / 256)  // 100
#define K1_BLKS (3 + W_SZ)                // 131
#define GATE_JPB 4                        // j's per K_B gate block (1 wave each)
#define GATE_BLKS (H_SZ / GATE_JPB)       // 512

// ws layout (floats)
#define WS_CTRL 0      // 3 ctrl logits
#define WS_SIN  16     // 128 stack_input (tanh'd), float4-aligned
#define WS_PART 160    // 6*2048 partial sums (bias included): gi_r,gi_z,gi_n,gh_r,gh_z,gh_n

typedef float f4 __attribute__((ext_vector_type(4)));

__device__ __forceinline__ float dot4(f4 a, f4 b) {
  return a.x * b.x + a.y * b.y + a.z * b.z + a.w * b.w;
}

// non-temporal: single-use weight streams stay out of L2 so the hidden/emb
// broadcast rows stay resident across all 2048 GEMV blocks.
__device__ __forceinline__ f4 ldnt(const f4* p) {
  return __builtin_nontemporal_load(p);
}

__device__ __forceinline__ float wave_reduce(float v) {
#pragma unroll
  for (int o = 32; o > 0; o >>= 1) v += __shfl_down(v, o, 64);
  return v;
}

__device__ __forceinline__ float half_reduce(float v) {  // 32-lane groups
#pragma unroll
  for (int o = 16; o > 0; o >>= 1) v += __shfl_down(v, o, 32);
  return v;
}

__device__ __forceinline__ void ctrl_softmax(const float* __restrict__ ws,
                                             float& c0, float& c1, float& c2) {
  const float l0 = ws[WS_CTRL + 0], l1 = ws[WS_CTRL + 1], l2 = ws[WS_CTRL + 2];
  const float m = fmaxf(l0, fmaxf(l1, l2));
  const float e0 = __expf(l0 - m), e1 = __expf(l1 - m), e2 = __expf(l2 - m);
  const float inv = 1.f / (e0 + e1 + e2);
  c0 = e0 * inv; c1 = e1 * inv; c2 = e2 * inv;
}

// ---------------------------------------------------------------------------
// K_A: all work with NO internal dependencies.
//  blocks 0..130          : ctrl logits (3) + stack_input rows (128)
//  blocks 131..131+2047   : GRU GEMV partials for row j — 6 dots over the
//                           ws-independent parts of x (emb row, 512 chunks)
//                           and h (512 chunks). Tail (stack_top, 32 chunks)
//                           deferred to K_B. Biases folded in here.
// ---------------------------------------------------------------------------
__global__ __launch_bounds__(256) void kA(
    const int* __restrict__ inp,
    const float* __restrict__ hidden,
    const float* __restrict__ emb,
    const float* __restrict__ ctrl_W,
    const float* __restrict__ ctrl_b,
    const float* __restrict__ sin_W,
    const float* __restrict__ sin_b,
    const float* __restrict__ w_ih,
    const float* __restrict__ w_hh,
    const float* __restrict__ b_ih,
    const float* __restrict__ b_hh,
    float* __restrict__ ws) {
  const int tid = threadIdx.x;

  if (blockIdx.x < K1_BLKS) {
    const int b = blockIdx.x;   // 0..130
    const float* row = (b < 3) ? (ctrl_W + (size_t)b * H_SZ)
                               : (sin_W + (size_t)(b - 3) * H_SZ);
    const f4* rw4 = (const f4*)row;
    const f4* rh4 = (const f4*)hidden;
    float acc = dot4(rw4[tid], rh4[tid]) + dot4(rw4[tid + 256], rh4[tid + 256]);
    acc = wave_reduce(acc);
    __shared__ float red1[4];
    const int wv_id = tid >> 6;
    if ((tid & 63) == 0) red1[wv_id] = acc;
    __syncthreads();
    if (tid == 0) {
      float total = red1[0] + red1[1] + red1[2] + red1[3];
      if (b < 3) ws[WS_CTRL + b] = total + ctrl_b[b];
      else       ws[WS_SIN + (b - 3)] = tanhf(total + sin_b[b - 3]);
    }
    return;
  }

  const int j = blockIdx.x - K1_BLKS;

  // prefetch biases early (consumed only by tid 0 at the end)
  float bi0 = 0.f, bi1 = 0.f, bi2 = 0.f, bh0 = 0.f, bh1 = 0.f, bh2 = 0.f;
  if (tid == 0) {
    bi0 = b_ih[j]; bi1 = b_ih[j + H_SZ]; bi2 = b_ih[j + 2 * H_SZ];
    bh0 = b_hh[j]; bh1 = b_hh[j + H_SZ]; bh2 = b_hh[j + 2 * H_SZ];
  }

  float a0 = 0.f, a1 = 0.f, a2 = 0.f, a3 = 0.f, a4 = 0.f, a5 = 0.f;

  const f4* wi0 = (const f4*)(w_ih + (size_t)j * X_SZ);
  const f4* wi1 = (const f4*)(w_ih + (size_t)(j + H_SZ) * X_SZ);
  const f4* wi2 = (const f4*)(w_ih + (size_t)(j + 2 * H_SZ) * X_SZ);
  const f4* emb4 = (const f4*)(emb + (size_t)inp[0] * H_SZ);
#pragma unroll
  for (int q = 0; q < 2; ++q) {
    const int c = tid + q * 256;
    const f4 xv = emb4[c];
    a0 += dot4(ldnt(wi0 + c), xv);
    a1 += dot4(ldnt(wi1 + c), xv);
    a2 += dot4(ldnt(wi2 + c), xv);
  }

  const f4* wh0 = (const f4*)(w_hh + (size_t)j * H_SZ);
  const f4* wh1 = (const f4*)(w_hh + (size_t)(j + H_SZ) * H_SZ);
  const f4* wh2 = (const f4*)(w_hh + (size_t)(j + 2 * H_SZ) * H_SZ);
  const f4* h4 = (const f4*)hidden;
#pragma unroll
  for (int q = 0; q < 2; ++q) {
    const int c = tid + q * 256;
    const f4 hv = h4[c];
    a3 += dot4(ldnt(wh0 + c), hv);
    a4 += dot4(ldnt(wh1 + c), hv);
    a5 += dot4(ldnt(wh2 + c), hv);
  }

  a0 = wave_reduce(a0); a1 = wave_reduce(a1); a2 = wave_reduce(a2);
  a3 = wave_reduce(a3); a4 = wave_reduce(a4); a5 = wave_reduce(a5);
  __shared__ float red[4][6];
  const int wv_id = tid >> 6;
  if ((tid & 63) == 0) {
    red[wv_id][0] = a0; red[wv_id][1] = a1; red[wv_id][2] = a2;
    red[wv_id][3] = a3; red[wv_id][4] = a4; red[wv_id][5] = a5;
  }
  __syncthreads();
  if (tid == 0) {
    float* p = ws + WS_PART + 6 * j;
    p[0] = red[0][0] + red[1][0] + red[2][0] + red[3][0] + bi0;
    p[1] = red[0][1] + red[1][1] + red[2][1] + red[3][1] + bi1;
    p[2] = red[0][2] + red[1][2] + red[2][2] + red[3][2] + bi2;
    p[3] = red[0][3] + red[1][3] + red[2][3] + red[3][3] + bh0;
    p[4] = red[0][4] + red[1][4] + red[2][4] + red[3][4] + bh1;
    p[5] = red[0][5] + red[1][5] + red[2][5] + red[3][5] + bh2;
  }
}

// ---------------------------------------------------------------------------
// K_B: everything that depends on K_A's ws.
//  blocks 0..99    : new_stack (25600 elems)
//  blocks 100..611 : per wave one j — tail dots (w_ih cols 2048..2175 over
//                    stack_top) + gate nonlinearity + h_new[j] -> out
// ---------------------------------------------------------------------------
__global__ __launch_bounds__(256) void kB(
    const float* __restrict__ hidden,
    const float* __restrict__ stack,
    const float* __restrict__ w_ih,
    float* __restrict__ ws,
    float* __restrict__ out) {
  const int tid = threadIdx.x;

  if (blockIdx.x < STACK_BLKS) {
    const int i = blockIdx.x * 256 + tid;   // 0 .. 25599
    float c0, c1, c2;
    ctrl_softmax(ws, c0, c1, c2);
    const int d = i >> 7;
    const int w = i & (W_SZ - 1);
    const float s = stack[i];
    const float up = (d == 0) ? ws[WS_SIN + w] : stack[i - W_SZ];
    const float dn = (d == D_SZ - 1) ? 0.f : stack[i + W_SZ];
    out[V_SZ + H_SZ + i] = c2 * s + c0 * up + c1 * dn;
    return;
  }

  const int wv = tid >> 6;
  const int lane = tid & 63;
  const int j = (blockIdx.x - STACK_BLKS) * GATE_JPB + wv;
  const int half = lane >> 5;
  const int c = lane & 31;          // f4 chunk 0..31 covering 128 floats

  float hj = 0.f;
  if (lane == 0) hj = hidden[j];    // prefetch

  // stack_top chunk c
  float c0, c1, c2;
  ctrl_softmax(ws, c0, c1, c2);
  const f4 s0 = *(const f4*)(stack + 4 * c);
  const f4 s1 = *(const f4*)(stack + W_SZ + 4 * c);
  const f4 sv = *(const f4*)(ws + WS_SIN + 4 * c);
  f4 xv;
  xv.x = c2 * s0.x + c0 * sv.x + c1 * s1.x;
  xv.y = c2 * s0.y + c0 * sv.y + c1 * s1.y;
  xv.z = c2 * s0.z + c0 * sv.z + c1 * s1.z;
  xv.w = c2 * s0.w + c0 * sv.w + c1 * s1.w;

  const f4* t0 = (const f4*)(w_ih + (size_t)j * X_SZ + H_SZ);
  const f4* t1 = (const f4*)(w_ih + (size_t)(j + H_SZ) * X_SZ + H_SZ);
  const f4* t2 = (const f4*)(w_ih + (size_t)(j + 2 * H_SZ) * X_SZ + H_SZ);

  // pass 1: lanes 0..31 -> row j, lanes 32..63 -> row j+H
  float v01 = dot4(ldnt((half ? t1 : t0) + c), xv);
  // pass 2: lanes 0..31 -> row j+2H
  float v2 = half ? 0.f : dot4(ldnt(t2 + c), xv);

  v01 = half_reduce(v01);           // lane0 -> d0, lane32 -> d1
  v2 = half_reduce(v2);             // lane0 -> d2
  const float d1 = __shfl(v01, 32, 64);

  if (lane == 0) {
    const float* p = ws + WS_PART + 6 * j;
    const float gi_r = p[0] + v01;
    const float gi_z = p[1] + d1;
    const float gi_n = p[2] + v2;
    const float gh_r = p[3];
    const float gh_z = p[4];
    const float gh_n = p[5];
    const float r = 1.f / (1.f + __expf(-(gi_r + gh_r)));
    const float z = 1.f / (1.f + __expf(-(gi_z + gh_z)));
    const float n = tanhf(gi_n + r * gh_n);
    out[V_SZ + j] = (1.f - z) * n + z * hj;
  }
}

// ---------------------------------------------------------------------------
// K_C: 45 blocks -> output logits = h_new @ dec_W.T + dec_b
// (h_new read back from out[V_SZ..])
// ---------------------------------------------------------------------------
__global__ __launch_bounds__(256) void kC(
    const float* __restrict__ dec_W,
    const float* __restrict__ dec_b,
    float* __restrict__ out) {
  const int v = blockIdx.x;
  const int tid = threadIdx.x;
  float db = 0.f;
  if (tid == 0) db = dec_b[v];
  const f4* row = (const f4*)(dec_W + (size_t)v * H_SZ);
  const f4* h4 = (const f4*)(out + V_SZ);
  float acc = dot4(row[tid], h4[tid]) + dot4(row[tid + 256], h4[tid + 256]);
  acc = wave_reduce(acc);
  __shared__ float red[4];
  const int wv_id = tid >> 6;
  if ((tid & 63) == 0) red[wv_id] = acc;
  __syncthreads();
  if (tid == 0) out[v] = red[0] + red[1] + red[2] + red[3] + db;
}

extern "C" void kernel_launch(void* const* d_in, const int* in_sizes, int n_in,
                              void* d_out, int out_size, void* d_ws, size_t ws_size,
                              hipStream_t stream) {
  const int*   inp    = (const int*)d_in[0];
  const float* hidden = (const float*)d_in[1];
  const float* stack  = (const float*)d_in[2];
  const float* emb    = (const float*)d_in[3];
  const float* ctrl_W = (const float*)d_in[4];
  const float* ctrl_b = (const float*)d_in[5];
  const float* sin_W  = (const float*)d_in[6];
  const float* sin_b  = (const float*)d_in[7];
  const float* w_ih   = (const float*)d_in[8];
  const float* w_hh   = (const float*)d_in[9];
  const float* b_ih   = (const float*)d_in[10];
  const float* b_hh   = (const float*)d_in[11];
  const float* dec_W  = (const float*)d_in[12];
  const float* dec_b  = (const float*)d_in[13];
  float* out = (float*)d_out;
  float* ws = (float*)d_ws;

  kA<<<K1_BLKS + H_SZ, 256, 0, stream>>>(inp, hidden, emb, ctrl_W, ctrl_b,
                                         sin_W, sin_b, w_ih, w_hh, b_ih, b_hh, ws);
  kB<<<STACK_BLKS + GATE_BLKS, 256, 0, stream>>>(hidden, stack, w_ih, ws, out);
  kC<<<V_SZ, 256, 0, stream>>>(dec_W, dec_b, out);
}